// Round 1
// baseline (911.848 us; speedup 1.0000x reference)
//
#include <hip/hip_runtime.h>

// NavAssignNet on MI355X.
// Structure:
//   - Wc[pass] = Wp @ Wb[pass] precomputed (kills edge_h materialization, K 256->128)
//   - 6 "bigpass" kernels: bf16 MFMA GEMM (64x256x128 per WG) fused with bias+relu+mean
//   - residual/LN path in fp32 (512x256 row-GEMMs, 4 rows/WG, LN fused)
//   - sinkhorn: 1 kernel, 8 WGs, LDS 64x65

typedef short bf16x8 __attribute__((ext_vector_type(8)));
typedef float f32x4 __attribute__((ext_vector_type(4)));

#define DEV static __device__ __forceinline__

DEV unsigned short f2bf(float x) {
    unsigned u = __float_as_uint(x);
    return (unsigned short)((u + 0x7fffu + ((u >> 16) & 1u)) >> 16);
}

// ---- 1. edge_raw -> bf16 (4.2M elems, 8/thread) ----
__global__ __launch_bounds__(256) void k_cast_edge(const float* __restrict__ in,
                                                   unsigned short* __restrict__ out) {
    int t = blockIdx.x * 256 + threadIdx.x;          // 524288 threads
    const float4* p = (const float4*)in + 2 * t;
    float4 a = p[0], b = p[1];
    ushort4 r0 = make_ushort4(f2bf(a.x), f2bf(a.y), f2bf(a.z), f2bf(a.w));
    ushort4 r1 = make_ushort4(f2bf(b.x), f2bf(b.y), f2bf(b.z), f2bf(b.w));
    ushort4* q = (ushort4*)out + 2 * t;
    q[0] = r0; q[1] = r1;
}

// ---- 2. target_raw = edge_raw.mean(axis=1) ----
__global__ __launch_bounds__(256) void k_target_mean(const float* __restrict__ edge,
                                                     float* __restrict__ traw) {
    int t = blockIdx.x * 256 + threadIdx.x;          // 65536
    int d = t & 127, j = (t >> 7) & 63, b = t >> 13;
    const float* p = edge + (b * 64 * 64 + j) * 128 + d;
    float s = 0.f;
#pragma unroll 8
    for (int i = 0; i < 64; ++i) s += p[i * 64 * 128];
    traw[(b * 64 + j) * 128 + d] = s * (1.f / 64.f);
}

// ---- 3. robot_h / target_h = X @ Wp + bp  (rows 0..511 robot, 512..1023 target) ----
__global__ __launch_bounds__(256) void k_proj(const float* __restrict__ robot_raw,
                                              const float* __restrict__ traw,
                                              const float* __restrict__ Wp,
                                              const float* __restrict__ bp,
                                              float* __restrict__ robot_h,
                                              float* __restrict__ target_h) {
    int h = threadIdx.x;
    int r0 = blockIdx.x * 4;                         // 256 blocks
    const float* in;
    float* out;
    if (r0 < 512) { in = robot_raw + r0 * 128; out = robot_h + r0 * 256; }
    else          { in = traw + (r0 - 512) * 128; out = target_h + (r0 - 512) * 256; }
    float a0 = 0, a1 = 0, a2 = 0, a3 = 0;
    for (int k = 0; k < 128; ++k) {
        float w = Wp[k * 256 + h];
        a0 += in[k] * w; a1 += in[128 + k] * w; a2 += in[256 + k] * w; a3 += in[384 + k] * w;
    }
    float b = bp[h];
    out[h] = a0 + b; out[256 + h] = a1 + b; out[512 + h] = a2 + b; out[768 + h] = a3 + b;
}

// ---- 4. WcT[p][h][d] = (Wp @ Wb_p)^T (bf16), bc[p][h] = bp@Wb_p + b_msg ----
__global__ __launch_bounds__(256) void k_wc(const float* __restrict__ Wp,
                                            const float* __restrict__ bp,
                                            const float* __restrict__ W_r2t,
                                            const float* __restrict__ b_r2t,
                                            const float* __restrict__ W_t2r,
                                            const float* __restrict__ b_t2r,
                                            unsigned short* __restrict__ WcT,
                                            float* __restrict__ bc) {
    int blk = blockIdx.x;
    int h = threadIdx.x;
    if (blk < 768) {
        int p = blk >> 7, d = blk & 127, l = p >> 1;
        const float* Wb = ((p & 1) ? W_t2r : W_r2t) + l * 512 * 256 + 256 * 256;
        float acc = 0.f;
        for (int k = 0; k < 256; ++k) acc += Wp[d * 256 + k] * Wb[k * 256 + h];
        WcT[p * 32768 + h * 128 + d] = f2bf(acc);
    } else {
        int p = blk - 768, l = p >> 1;
        const float* Wb = ((p & 1) ? W_t2r : W_r2t) + l * 512 * 256 + 256 * 256;
        const float* bm = ((p & 1) ? b_t2r : b_r2t) + l * 256;
        float acc = bm[h];
        for (int k = 0; k < 256; ++k) acc += bp[k] * Wb[k * 256 + h];
        bc[p * 256 + h] = acc;
    }
}

// ---- 5. rowgemm: out[row][h] = in[row][:K] @ W[:,h] (+bias); optional transposed store ----
__global__ __launch_bounds__(256) void k_rowgemm(const float* __restrict__ in,
                                                 const float* __restrict__ W,
                                                 const float* __restrict__ bias,
                                                 float* __restrict__ out,
                                                 int K, int trans) {
    int h = threadIdx.x;
    int r0 = blockIdx.x * 4;
    const float* i0 = in + (long)r0 * K;
    const float* i1 = i0 + K;
    const float* i2 = i1 + K;
    const float* i3 = i2 + K;
    float a0 = 0, a1 = 0, a2 = 0, a3 = 0;
    for (int k = 0; k < K; ++k) {
        float w = W[k * 256 + h];
        a0 += i0[k] * w; a1 += i1[k] * w; a2 += i2[k] * w; a3 += i3[k] * w;
    }
    if (bias) { float b = bias[h]; a0 += b; a1 += b; a2 += b; a3 += b; }
    if (!trans) {
        out[(r0 + 0) * 256 + h] = a0;
        out[(r0 + 1) * 256 + h] = a1;
        out[(r0 + 2) * 256 + h] = a2;
        out[(r0 + 3) * 256 + h] = a3;
    } else {
        // tST[b][h][j]: row = b*64+j
        int b0 = r0 >> 6;
        float* o = out + (b0 * 256 + h) * 64;
        o[(r0 + 0) & 63] = a0; o[(r0 + 1) & 63] = a1; o[(r0 + 2) & 63] = a2; o[(r0 + 3) & 63] = a3;
    }
}

// ---- 6. state update: state = LN(state + [state;agg]@W + b) ----
__global__ __launch_bounds__(256) void k_update(float* __restrict__ state,
                                                const float* __restrict__ agg,
                                                const float* __restrict__ W,
                                                const float* __restrict__ bvec,
                                                const float* __restrict__ g,
                                                const float* __restrict__ be) {
    int h = threadIdx.x;
    int r0 = blockIdx.x * 4;
    const float* s0 = state + r0 * 256;
    const float* a0 = agg + r0 * 256;
    float b = bvec[h];
    float c0 = b, c1 = b, c2 = b, c3 = b;
    for (int k = 0; k < 256; ++k) {
        float w = W[k * 256 + h];
        c0 += s0[k] * w; c1 += s0[256 + k] * w; c2 += s0[512 + k] * w; c3 += s0[768 + k] * w;
    }
    for (int k = 0; k < 256; ++k) {
        float w = W[(256 + k) * 256 + h];
        c0 += a0[k] * w; c1 += a0[256 + k] * w; c2 += a0[512 + k] * w; c3 += a0[768 + k] * w;
    }
    float x[4];
    x[0] = s0[h] + c0; x[1] = s0[256 + h] + c1; x[2] = s0[512 + h] + c2; x[3] = s0[768 + h] + c3;

    __shared__ float red[2][4][4];
    int w64 = threadIdx.x >> 6, lane = threadIdx.x & 63;
#pragma unroll
    for (int r = 0; r < 4; ++r) {
        float s = x[r], q = x[r] * x[r];
#pragma unroll
        for (int m = 1; m < 64; m <<= 1) { s += __shfl_xor(s, m); q += __shfl_xor(q, m); }
        if (lane == 0) { red[0][w64][r] = s; red[1][w64][r] = q; }
    }
    __syncthreads();
    float gg = g[h], bb = be[h];
    float y[4];
#pragma unroll
    for (int r = 0; r < 4; ++r) {
        float s = red[0][0][r] + red[0][1][r] + red[0][2][r] + red[0][3][r];
        float q = red[1][0][r] + red[1][1][r] + red[1][2][r] + red[1][3][r];
        float m = s * (1.f / 256.f);
        float v = q * (1.f / 256.f) - m * m;
        y[r] = (x[r] - m) * rsqrtf(v + 1e-5f) * gg + bb;
    }
    float* so = state + r0 * 256;
    so[h] = y[0]; so[256 + h] = y[1]; so[512 + h] = y[2]; so[768 + h] = y[3];
}

// ---- 7. bigpass: agg[b,jj,h] = mean_rows relu(edge_raw@Wc + rowbias + bc), MFMA bf16 ----
// mode 0 (r2t): WG=(b,j), rows=i (stride 8192);  mode 1 (t2r): WG=(b,i), rows=j (stride 128)
__global__ __launch_bounds__(256) void k_bigpass(const unsigned short* __restrict__ edge_bf,
                                                 const unsigned short* __restrict__ WcT,
                                                 const float* __restrict__ bc,
                                                 const float* __restrict__ rowbias,
                                                 float* __restrict__ agg,
                                                 int mode) {
    int wg = blockIdx.x;                 // 512 = b*64 + jj
    int b = wg >> 6, jj = wg & 63;
    int w = threadIdx.x >> 6, lane = threadIdx.x & 63;
    int row16 = lane & 15, kgrp = lane >> 4;

    int rstride = (mode == 0) ? 8192 : 128;
    const unsigned short* A = edge_bf + b * 524288 + ((mode == 0) ? jj * 128 : jj * 8192);
    const unsigned short* Ap = A + row16 * rstride + 8 * kgrp;
    const unsigned short* Bp = WcT + (64 * w + row16) * 128 + 8 * kgrp;

    f32x4 acc[4][4];
#pragma unroll
    for (int mi = 0; mi < 4; ++mi)
#pragma unroll
        for (int ni = 0; ni < 4; ++ni) acc[mi][ni] = f32x4{0.f, 0.f, 0.f, 0.f};

#pragma unroll
    for (int kk = 0; kk < 4; ++kk) {
        bf16x8 av[4], bv[4];
#pragma unroll
        for (int mi = 0; mi < 4; ++mi)
            av[mi] = *(const bf16x8*)(Ap + mi * 16 * rstride + kk * 32);
#pragma unroll
        for (int ni = 0; ni < 4; ++ni)
            bv[ni] = *(const bf16x8*)(Bp + ni * 16 * 128 + kk * 32);
#pragma unroll
        for (int mi = 0; mi < 4; ++mi)
#pragma unroll
            for (int ni = 0; ni < 4; ++ni)
                acc[mi][ni] = __builtin_amdgcn_mfma_f32_16x16x32_bf16(av[mi], bv[ni], acc[mi][ni], 0, 0, 0);
    }

    // epilogue: + rowbias[row][col] + bc[col], relu, sum over 64 rows
    const float* rb = rowbias + (b * 64) * 256;
    float colsum[4] = {0.f, 0.f, 0.f, 0.f};
#pragma unroll
    for (int ni = 0; ni < 4; ++ni) {
        int col = 64 * w + 16 * ni + row16;
        float bch = bc[col];
#pragma unroll
        for (int mi = 0; mi < 4; ++mi) {
            int rbase = 16 * mi + 4 * kgrp;
#pragma unroll
            for (int r = 0; r < 4; ++r) {
                float v = acc[mi][ni][r] + rb[(rbase + r) * 256 + col] + bch;
                colsum[ni] += fmaxf(v, 0.f);
            }
        }
    }
#pragma unroll
    for (int ni = 0; ni < 4; ++ni) {
        colsum[ni] += __shfl_xor(colsum[ni], 16);
        colsum[ni] += __shfl_xor(colsum[ni], 32);
    }
    if (kgrp == 0) {
        float* o = agg + (b * 64 + jj) * 256 + 64 * w + row16;
#pragma unroll
        for (int ni = 0; ni < 4; ++ni) o[16 * ni] = colsum[ni] * (1.f / 64.f);
    }
}

// ---- 8. scores[b,i,j] = sum_h relu(rS[b,i,h] + tST[b,h,j]) * Ws2[h] + bs2 ----
__global__ __launch_bounds__(256) void k_scores(const float* __restrict__ rS,
                                                const float* __restrict__ tST,
                                                const float* __restrict__ Ws2,
                                                const float* __restrict__ bs2,
                                                float* __restrict__ scores) {
    int t = blockIdx.x * 256 + threadIdx.x;          // 32768
    int j = t & 63, i = (t >> 6) & 63, b = t >> 12;
    const float* rs = rS + (b * 64 + i) * 256;       // wave-uniform
    const float* ts = tST + b * 256 * 64 + j;        // coalesced over lanes
    float acc = bs2[0];
    for (int h = 0; h < 256; ++h)
        acc += fmaxf(rs[h] + ts[h * 64], 0.f) * Ws2[h];
    scores[t] = acc;
}

// ---- 9. sinkhorn: 10 iters row/col LSE + exp; 1 WG per batch ----
__global__ __launch_bounds__(256) void k_sinkhorn(const float* __restrict__ scores,
                                                  float* __restrict__ probs) {
    int b = blockIdx.x;
    int w = threadIdx.x >> 6, lane = threadIdx.x & 63;
    __shared__ float S[64][65];
    for (int r = w; r < 64; r += 4) S[r][lane] = scores[(b * 64 + r) * 64 + lane];
    __syncthreads();
    for (int it = 0; it < 10; ++it) {
        for (int r = w * 16; r < w * 16 + 16; ++r) {   // LSE over j (axis -1)
            float v = S[r][lane];
            float m = v;
#pragma unroll
            for (int s = 1; s < 64; s <<= 1) m = fmaxf(m, __shfl_xor(m, s));
            float e = __expf(v - m), ss = e;
#pragma unroll
            for (int s = 1; s < 64; s <<= 1) ss += __shfl_xor(ss, s);
            S[r][lane] = v - (m + __logf(ss));
        }
        __syncthreads();
        for (int c = w * 16; c < w * 16 + 16; ++c) {   // LSE over i (axis -2)
            float v = S[lane][c];
            float m = v;
#pragma unroll
            for (int s = 1; s < 64; s <<= 1) m = fmaxf(m, __shfl_xor(m, s));
            float e = __expf(v - m), ss = e;
#pragma unroll
            for (int s = 1; s < 64; s <<= 1) ss += __shfl_xor(ss, s);
            S[lane][c] = v - (m + __logf(ss));
        }
        __syncthreads();
    }
    for (int r = w; r < 64; r += 4) probs[(b * 64 + r) * 64 + lane] = __expf(S[r][lane]);
}

extern "C" void kernel_launch(void* const* d_in, const int* in_sizes, int n_in,
                              void* d_out, int out_size, void* d_ws, size_t ws_size,
                              hipStream_t stream) {
    const float* robot_raw = (const float*)d_in[0];
    const float* edge_raw  = (const float*)d_in[1];
    const float* Wp    = (const float*)d_in[2];
    const float* bp    = (const float*)d_in[3];
    const float* W_r2t = (const float*)d_in[4];
    const float* b_r2t = (const float*)d_in[5];
    const float* W_pt  = (const float*)d_in[6];
    const float* b_pt  = (const float*)d_in[7];
    const float* g_t   = (const float*)d_in[8];
    const float* be_t  = (const float*)d_in[9];
    const float* W_t2r = (const float*)d_in[10];
    const float* b_t2r = (const float*)d_in[11];
    const float* W_pr  = (const float*)d_in[12];
    const float* b_pr  = (const float*)d_in[13];
    const float* g_r   = (const float*)d_in[14];
    const float* be_r  = (const float*)d_in[15];
    const float* Ws1   = (const float*)d_in[16];
    const float* bs1   = (const float*)d_in[17];
    const float* Ws2   = (const float*)d_in[18];
    const float* bs2   = (const float*)d_in[19];

    char* ws = (char*)d_ws;
    unsigned short* edge_bf = (unsigned short*)(ws);            // 8,388,608 B
    float* traw     = (float*)(ws + 8388608);                   //   262,144
    float* robot_h  = (float*)(ws + 8650752);                   //   524,288
    float* target_h = (float*)(ws + 9175040);                   //   524,288
    unsigned short* WcT = (unsigned short*)(ws + 9699328);      //   393,216
    float* bc       = (float*)(ws + 10092544);                  //     6,144
    float* rWa      = (float*)(ws + 10098688);                  //   524,288
    float* tWa      = (float*)(ws + 10622976);                  //   524,288
    float* agg      = (float*)(ws + 11147264);                  //   524,288
    float* rS       = (float*)(ws + 11671552);                  //   524,288
    float* tST      = (float*)(ws + 12195840);                  //   524,288

    float* out    = (float*)d_out;
    float* probs  = out;            // output 0: sinkhorn(scores)
    float* scores = out + 32768;    // output 1: scores

    hipLaunchKernelGGL(k_cast_edge, dim3(2048), dim3(256), 0, stream, edge_raw, edge_bf);
    hipLaunchKernelGGL(k_target_mean, dim3(256), dim3(256), 0, stream, edge_raw, traw);
    hipLaunchKernelGGL(k_proj, dim3(256), dim3(256), 0, stream, robot_raw, traw, Wp, bp, robot_h, target_h);
    hipLaunchKernelGGL(k_wc, dim3(774), dim3(256), 0, stream, Wp, bp, W_r2t, b_r2t, W_t2r, b_t2r, WcT, bc);

    for (int l = 0; l < 3; ++l) {
        hipLaunchKernelGGL(k_rowgemm, dim3(128), dim3(256), 0, stream,
                           robot_h, W_r2t + l * 512 * 256, (const float*)nullptr, rWa, 256, 0);
        hipLaunchKernelGGL(k_bigpass, dim3(512), dim3(256), 0, stream,
                           edge_bf, WcT + (2 * l) * 32768, bc + (2 * l) * 256, rWa, agg, 0);
        hipLaunchKernelGGL(k_update, dim3(128), dim3(256), 0, stream,
                           target_h, agg, W_pt + l * 512 * 256, b_pt + l * 256, g_t + l * 256, be_t + l * 256);
        hipLaunchKernelGGL(k_rowgemm, dim3(128), dim3(256), 0, stream,
                           target_h, W_t2r + l * 512 * 256, (const float*)nullptr, tWa, 256, 0);
        hipLaunchKernelGGL(k_bigpass, dim3(512), dim3(256), 0, stream,
                           edge_bf, WcT + (2 * l + 1) * 32768, bc + (2 * l + 1) * 256, tWa, agg, 1);
        hipLaunchKernelGGL(k_update, dim3(128), dim3(256), 0, stream,
                           robot_h, agg, W_pr + l * 512 * 256, b_pr + l * 256, g_r + l * 256, be_r + l * 256);
    }

    hipLaunchKernelGGL(k_rowgemm, dim3(128), dim3(256), 0, stream,
                       robot_h, Ws1, (const float*)nullptr, rS, 256, 0);
    hipLaunchKernelGGL(k_rowgemm, dim3(128), dim3(256), 0, stream,
                       target_h, Ws1 + 256 * 256, bs1, tST, 256, 1);
    hipLaunchKernelGGL(k_scores, dim3(128), dim3(256), 0, stream, rS, tST, Ws2, bs2, scores);
    hipLaunchKernelGGL(k_sinkhorn, dim3(8), dim3(256), 0, stream, scores, probs);
}

// Round 2
// 447.408 us; speedup vs baseline: 2.0381x; 2.0381x over previous
//
#include <hip/hip_runtime.h>

// NavAssignNet on MI355X — round 2.
//   - fused cast+mean single pass over edge_raw
//   - Wc[pass] = Wp @ Wb[pass] precomputed (K 256->128, no edge_h)
//   - 6 bigpass: bf16 MFMA (64x256x128 per WG) fused bias+relu+mean
//   - k_update fused with next rowgemm(s) via LDS-staged LN rows
//   - sinkhorn: register-resident, ILP row-LSE + local col-LSE

typedef short bf16x8 __attribute__((ext_vector_type(8)));
typedef float f32x4 __attribute__((ext_vector_type(4)));

#define DEV static __device__ __forceinline__

DEV unsigned short f2bf(float x) {
    unsigned u = __float_as_uint(x);
    return (unsigned short)((u + 0x7fffu + ((u >> 16) & 1u)) >> 16);
}

// ---- 1. prep: edge_raw -> bf16 AND traw = edge_raw.mean(axis=1) in one pass ----
// thread t: b = t>>12, j = (t>>6)&63, dq = t&63 (d = 2*dq). Loop i=0..63.
__global__ __launch_bounds__(256) void k_prep(const float* __restrict__ edge,
                                              unsigned short* __restrict__ edge_bf,
                                              float* __restrict__ traw) {
    int t = blockIdx.x * 256 + threadIdx.x;          // 32768 threads, 128 WGs
    int dq = t & 63, j = (t >> 6) & 63, b = t >> 12;
    long base = ((long)(b * 64) * 64 + j) * 128 + 2 * dq;
    float sx = 0.f, sy = 0.f;
#pragma unroll 8
    for (int i = 0; i < 64; ++i) {
        long idx = base + (long)i * 8192;
        float2 v = *(const float2*)(edge + idx);
        sx += v.x; sy += v.y;
        ushort2 r = make_ushort2(f2bf(v.x), f2bf(v.y));
        *(ushort2*)(edge_bf + idx) = r;
    }
    float2 m = make_float2(sx * (1.f / 64.f), sy * (1.f / 64.f));
    *(float2*)(traw + (b * 64 + j) * 128 + 2 * dq) = m;
}

// ---- 2. WcT[p][h][d] = (Wp @ Wb_p)^T (bf16), bc[p][h] = bp@Wb_p + b_msg ----
__global__ __launch_bounds__(256) void k_wc(const float* __restrict__ Wp,
                                            const float* __restrict__ bp,
                                            const float* __restrict__ W_r2t,
                                            const float* __restrict__ b_r2t,
                                            const float* __restrict__ W_t2r,
                                            const float* __restrict__ b_t2r,
                                            unsigned short* __restrict__ WcT,
                                            float* __restrict__ bc) {
    int blk = blockIdx.x;
    int h = threadIdx.x;
    if (blk < 768) {
        int p = blk >> 7, d = blk & 127, l = p >> 1;
        const float* Wb = ((p & 1) ? W_t2r : W_r2t) + l * 512 * 256 + 256 * 256;
        float acc = 0.f;
        for (int k = 0; k < 256; ++k) acc += Wp[d * 256 + k] * Wb[k * 256 + h];
        WcT[p * 32768 + h * 128 + d] = f2bf(acc);
    } else {
        int p = blk - 768, l = p >> 1;
        const float* Wb = ((p & 1) ? W_t2r : W_r2t) + l * 512 * 256 + 256 * 256;
        const float* bm = ((p & 1) ? b_t2r : b_r2t) + l * 256;
        float acc = bm[h];
        for (int k = 0; k < 256; ++k) acc += bp[k] * Wb[k * 256 + h];
        bc[p * 256 + h] = acc;
    }
}

// ---- 3. proj: robot_h/target_h = X @ Wp + bp ; robot WGs also emit rWa0 ----
// 512 WGs x 2 rows. Rows 0..511 robot, 512..1023 target.
__global__ __launch_bounds__(256) void k_proj(const float* __restrict__ robot_raw,
                                              const float* __restrict__ traw,
                                              const float* __restrict__ Wp,
                                              const float* __restrict__ bp,
                                              const float* __restrict__ Wa0,
                                              float* __restrict__ robot_h,
                                              float* __restrict__ target_h,
                                              float* __restrict__ rWa) {
    int h = threadIdx.x;
    int r0 = blockIdx.x * 2;
    int robot = (r0 < 512);
    const float* in;
    float* out;
    if (robot) { in = robot_raw + r0 * 128; out = robot_h + r0 * 256; }
    else       { in = traw + (r0 - 512) * 128; out = target_h + (r0 - 512) * 256; }
    float a0 = 0, a1 = 0;
    for (int k = 0; k < 128; ++k) {
        float w = Wp[k * 256 + h];
        a0 += in[k] * w; a1 += in[128 + k] * w;
    }
    float b = bp[h];
    a0 += b; a1 += b;
    out[h] = a0; out[256 + h] = a1;

    __shared__ float yl[2][257];
    if (robot) { yl[0][h] = a0; yl[1][h] = a1; }
    __syncthreads();
    if (robot) {
        float c0 = 0, c1 = 0;
        for (int k = 0; k < 256; ++k) {
            float w = Wa0[k * 256 + h];
            c0 += yl[0][k] * w; c1 += yl[1][k] * w;
        }
        rWa[r0 * 256 + h] = c0; rWa[(r0 + 1) * 256 + h] = c1;
    }
}

// ---- 4. state update: state = LN(state + [state;agg]@W + b), fused next-GEMM(s) ----
// 128 WGs x 4 rows. W2a: out2a[row][h] = y@W2a (no bias). W2b: transposed +bias.
__global__ __launch_bounds__(256) void k_update(float* __restrict__ state,
                                                const float* __restrict__ agg,
                                                const float* __restrict__ W,
                                                const float* __restrict__ bvec,
                                                const float* __restrict__ g,
                                                const float* __restrict__ be,
                                                const float* __restrict__ W2a,
                                                float* __restrict__ out2a,
                                                const float* __restrict__ W2b,
                                                const float* __restrict__ b2b,
                                                float* __restrict__ out2b) {
    int h = threadIdx.x;
    int r0 = blockIdx.x * 4;
    const float* s0 = state + r0 * 256;
    const float* a0 = agg + r0 * 256;
    float b = bvec[h];
    float c0 = b, c1 = b, c2 = b, c3 = b;
    for (int k = 0; k < 256; ++k) {
        float w = W[k * 256 + h];
        c0 += s0[k] * w; c1 += s0[256 + k] * w; c2 += s0[512 + k] * w; c3 += s0[768 + k] * w;
    }
    for (int k = 0; k < 256; ++k) {
        float w = W[(256 + k) * 256 + h];
        c0 += a0[k] * w; c1 += a0[256 + k] * w; c2 += a0[512 + k] * w; c3 += a0[768 + k] * w;
    }
    float x[4];
    x[0] = s0[h] + c0; x[1] = s0[256 + h] + c1; x[2] = s0[512 + h] + c2; x[3] = s0[768 + h] + c3;

    __shared__ float red[2][4][4];
    __shared__ float yl[4][257];
    int w64 = threadIdx.x >> 6, lane = threadIdx.x & 63;
#pragma unroll
    for (int r = 0; r < 4; ++r) {
        float s = x[r], q = x[r] * x[r];
#pragma unroll
        for (int m = 1; m < 64; m <<= 1) { s += __shfl_xor(s, m); q += __shfl_xor(q, m); }
        if (lane == 0) { red[0][w64][r] = s; red[1][w64][r] = q; }
    }
    __syncthreads();
    float gg = g[h], bb = be[h];
    float* so = state + r0 * 256;
#pragma unroll
    for (int r = 0; r < 4; ++r) {
        float s = red[0][0][r] + red[0][1][r] + red[0][2][r] + red[0][3][r];
        float q = red[1][0][r] + red[1][1][r] + red[1][2][r] + red[1][3][r];
        float m = s * (1.f / 256.f);
        float v = q * (1.f / 256.f) - m * m;
        float y = (x[r] - m) * rsqrtf(v + 1e-5f) * gg + bb;
        so[r * 256 + h] = y;
        yl[r][h] = y;
    }
    __syncthreads();
    if (W2a) {
        float d0 = 0, d1 = 0, d2 = 0, d3 = 0;
        for (int k = 0; k < 256; ++k) {
            float w = W2a[k * 256 + h];
            d0 += yl[0][k] * w; d1 += yl[1][k] * w; d2 += yl[2][k] * w; d3 += yl[3][k] * w;
        }
        float* o = out2a + r0 * 256;
        o[h] = d0; o[256 + h] = d1; o[512 + h] = d2; o[768 + h] = d3;
    }
    if (W2b) {
        float bb2 = b2b[h];
        float d0 = bb2, d1 = bb2, d2 = bb2, d3 = bb2;
        for (int k = 0; k < 256; ++k) {
            float w = W2b[k * 256 + h];
            d0 += yl[0][k] * w; d1 += yl[1][k] * w; d2 += yl[2][k] * w; d3 += yl[3][k] * w;
        }
        // transposed store: out2b[b][h][j], row = b*64+j
        int b0 = r0 >> 6;
        float* o = out2b + (b0 * 256 + h) * 64;
        o[(r0 + 0) & 63] = d0; o[(r0 + 1) & 63] = d1; o[(r0 + 2) & 63] = d2; o[(r0 + 3) & 63] = d3;
    }
}

// ---- 5. bigpass: agg[b,jj,h] = mean_rows relu(edge_raw@Wc + rowbias + bc), MFMA bf16 ----
__global__ __launch_bounds__(256) void k_bigpass(const unsigned short* __restrict__ edge_bf,
                                                 const unsigned short* __restrict__ WcT,
                                                 const float* __restrict__ bc,
                                                 const float* __restrict__ rowbias,
                                                 float* __restrict__ agg,
                                                 int mode) {
    int wg = blockIdx.x;                 // 512 = b*64 + jj
    int b = wg >> 6, jj = wg & 63;
    int w = threadIdx.x >> 6, lane = threadIdx.x & 63;
    int row16 = lane & 15, kgrp = lane >> 4;

    int rstride = (mode == 0) ? 8192 : 128;
    const unsigned short* A = edge_bf + b * 524288 + ((mode == 0) ? jj * 128 : jj * 8192);
    const unsigned short* Ap = A + row16 * rstride + 8 * kgrp;
    const unsigned short* Bp = WcT + (64 * w + row16) * 128 + 8 * kgrp;

    f32x4 acc[4][4];
#pragma unroll
    for (int mi = 0; mi < 4; ++mi)
#pragma unroll
        for (int ni = 0; ni < 4; ++ni) acc[mi][ni] = f32x4{0.f, 0.f, 0.f, 0.f};

#pragma unroll
    for (int kk = 0; kk < 4; ++kk) {
        bf16x8 av[4], bv[4];
#pragma unroll
        for (int mi = 0; mi < 4; ++mi)
            av[mi] = *(const bf16x8*)(Ap + mi * 16 * rstride + kk * 32);
#pragma unroll
        for (int ni = 0; ni < 4; ++ni)
            bv[ni] = *(const bf16x8*)(Bp + ni * 16 * 128 + kk * 32);
#pragma unroll
        for (int mi = 0; mi < 4; ++mi)
#pragma unroll
            for (int ni = 0; ni < 4; ++ni)
                acc[mi][ni] = __builtin_amdgcn_mfma_f32_16x16x32_bf16(av[mi], bv[ni], acc[mi][ni], 0, 0, 0);
    }

    const float* rb = rowbias + (b * 64) * 256;
    float colsum[4] = {0.f, 0.f, 0.f, 0.f};
#pragma unroll
    for (int ni = 0; ni < 4; ++ni) {
        int col = 64 * w + 16 * ni + row16;
        float bch = bc[col];
#pragma unroll
        for (int mi = 0; mi < 4; ++mi) {
            int rbase = 16 * mi + 4 * kgrp;
#pragma unroll
            for (int r = 0; r < 4; ++r) {
                float v = acc[mi][ni][r] + rb[(rbase + r) * 256 + col] + bch;
                colsum[ni] += fmaxf(v, 0.f);
            }
        }
    }
#pragma unroll
    for (int ni = 0; ni < 4; ++ni) {
        colsum[ni] += __shfl_xor(colsum[ni], 16);
        colsum[ni] += __shfl_xor(colsum[ni], 32);
    }
    if (kgrp == 0) {
        float* o = agg + (b * 64 + jj) * 256 + 64 * w + row16;
#pragma unroll
        for (int ni = 0; ni < 4; ++ni) o[16 * ni] = colsum[ni] * (1.f / 64.f);
    }
}

// ---- 6. scores[b,i,j] = sum_h relu(rS[b,i,h] + tST[b,h,j]) * Ws2[h] + bs2 ----
__global__ __launch_bounds__(256) void k_scores(const float* __restrict__ rS,
                                                const float* __restrict__ tST,
                                                const float* __restrict__ Ws2,
                                                const float* __restrict__ bs2,
                                                float* __restrict__ scores) {
    int t = blockIdx.x * 256 + threadIdx.x;          // 32768
    int j = t & 63, i = (t >> 6) & 63, b = t >> 12;
    const float* rs = rS + (b * 64 + i) * 256;
    const float* ts = tST + b * 256 * 64 + j;
    float acc = bs2[0];
    for (int h = 0; h < 256; ++h)
        acc += fmaxf(rs[h] + ts[h * 64], 0.f) * Ws2[h];
    scores[t] = acc;
}

// ---- 7. sinkhorn: register-resident, parallel LSE ----
// thread (j = t&63, rg = t>>6) holds S[rg*16+k][j], k=0..15.
__global__ __launch_bounds__(256) void k_sinkhorn(const float* __restrict__ scores,
                                                  float* __restrict__ probs) {
    int b = blockIdx.x;
    int t = threadIdx.x;
    int j = t & 63, rg = t >> 6;
    float v[16];
    const float* src = scores + b * 4096 + rg * 1024 + j;
#pragma unroll
    for (int k = 0; k < 16; ++k) v[k] = src[k * 64];

    __shared__ float lm_s[4][64];
    __shared__ float ps_s[4][64];

    for (int it = 0; it < 10; ++it) {
        // row LSE (over j): 16 independent wave reductions -> ILP
#pragma unroll
        for (int k = 0; k < 16; ++k) {
            float m = v[k];
#pragma unroll
            for (int s = 1; s < 64; s <<= 1) m = fmaxf(m, __shfl_xor(m, s));
            float e = __expf(v[k] - m), ss = e;
#pragma unroll
            for (int s = 1; s < 64; s <<= 1) ss += __shfl_xor(ss, s);
            v[k] -= m + __logf(ss);
        }
        // col LSE (over i): local 16-elem partial + LDS combine over 4 row-groups
        float lm = v[0];
#pragma unroll
        for (int k = 1; k < 16; ++k) lm = fmaxf(lm, v[k]);
        float ps = 0.f;
#pragma unroll
        for (int k = 0; k < 16; ++k) ps += __expf(v[k] - lm);
        lm_s[rg][j] = lm; ps_s[rg][j] = ps;
        __syncthreads();
        float m0 = lm_s[0][j], m1 = lm_s[1][j], m2 = lm_s[2][j], m3 = lm_s[3][j];
        float M = fmaxf(fmaxf(m0, m1), fmaxf(m2, m3));
        float S = ps_s[0][j] * __expf(m0 - M) + ps_s[1][j] * __expf(m1 - M)
                + ps_s[2][j] * __expf(m2 - M) + ps_s[3][j] * __expf(m3 - M);
        float lse = M + __logf(S);
#pragma unroll
        for (int k = 0; k < 16; ++k) v[k] -= lse;
        __syncthreads();
    }
    float* dst = probs + b * 4096 + rg * 1024 + j;
#pragma unroll
    for (int k = 0; k < 16; ++k) dst[k * 64] = __expf(v[k]);
}

extern "C" void kernel_launch(void* const* d_in, const int* in_sizes, int n_in,
                              void* d_out, int out_size, void* d_ws, size_t ws_size,
                              hipStream_t stream) {
    const float* robot_raw = (const float*)d_in[0];
    const float* edge_raw  = (const float*)d_in[1];
    const float* Wp    = (const float*)d_in[2];
    const float* bp    = (const float*)d_in[3];
    const float* W_r2t = (const float*)d_in[4];
    const float* b_r2t = (const float*)d_in[5];
    const float* W_pt  = (const float*)d_in[6];
    const float* b_pt  = (const float*)d_in[7];
    const float* g_t   = (const float*)d_in[8];
    const float* be_t  = (const float*)d_in[9];
    const float* W_t2r = (const float*)d_in[10];
    const float* b_t2r = (const float*)d_in[11];
    const float* W_pr  = (const float*)d_in[12];
    const float* b_pr  = (const float*)d_in[13];
    const float* g_r   = (const float*)d_in[14];
    const float* be_r  = (const float*)d_in[15];
    const float* Ws1   = (const float*)d_in[16];
    const float* bs1   = (const float*)d_in[17];
    const float* Ws2   = (const float*)d_in[18];
    const float* bs2   = (const float*)d_in[19];

    char* ws = (char*)d_ws;
    unsigned short* edge_bf = (unsigned short*)(ws);            // 8,388,608 B
    float* traw     = (float*)(ws + 8388608);                   //   262,144
    float* robot_h  = (float*)(ws + 8650752);                   //   524,288
    float* target_h = (float*)(ws + 9175040);                   //   524,288
    unsigned short* WcT = (unsigned short*)(ws + 9699328);      //   393,216
    float* bc       = (float*)(ws + 10092544);                  //     6,144
    float* rWa      = (float*)(ws + 10098688);                  //   524,288
    float* tWa      = (float*)(ws + 10622976);                  //   524,288
    float* agg      = (float*)(ws + 11147264);                  //   524,288
    float* rS       = (float*)(ws + 11671552);                  //   524,288
    float* tST      = (float*)(ws + 12195840);                  //   524,288

    float* out    = (float*)d_out;
    float* probs  = out;            // output 0: sinkhorn(scores)
    float* scores = out + 32768;    // output 1: scores

    hipLaunchKernelGGL(k_prep, dim3(128), dim3(256), 0, stream, edge_raw, edge_bf, traw);
    hipLaunchKernelGGL(k_wc, dim3(774), dim3(256), 0, stream, Wp, bp, W_r2t, b_r2t, W_t2r, b_t2r, WcT, bc);
    hipLaunchKernelGGL(k_proj, dim3(512), dim3(256), 0, stream,
                       robot_raw, traw, Wp, bp, W_r2t /* layer 0 Wa */, robot_h, target_h, rWa);

    for (int l = 0; l < 3; ++l) {
        // r2t bigpass (uses rWa from proj or previous update_r)
        hipLaunchKernelGGL(k_bigpass, dim3(512), dim3(256), 0, stream,
                           edge_bf, WcT + (2 * l) * 32768, bc + (2 * l) * 256, rWa, agg, 0);
        // update target; fused tWa = target_h @ W_t2r[l][:256]; last layer also tST
        const float* W2b = (l == 2) ? (Ws1 + 256 * 256) : nullptr;
        const float* b2b = (l == 2) ? bs1 : nullptr;
        float* o2b = (l == 2) ? tST : nullptr;
        hipLaunchKernelGGL(k_update, dim3(128), dim3(256), 0, stream,
                           target_h, agg, W_pt + l * 512 * 256, b_pt + l * 256,
                           g_t + l * 256, be_t + l * 256,
                           W_t2r + l * 512 * 256, tWa, W2b, b2b, o2b);
        // t2r bigpass
        hipLaunchKernelGGL(k_bigpass, dim3(512), dim3(256), 0, stream,
                           edge_bf, WcT + (2 * l + 1) * 32768, bc + (2 * l + 1) * 256, tWa, agg, 1);
        // update robot; fused next rWa (l<2) or rS (l==2)
        const float* W2a = (l < 2) ? (W_r2t + (l + 1) * 512 * 256) : Ws1;
        float* o2a = (l < 2) ? rWa : rS;
        hipLaunchKernelGGL(k_update, dim3(128), dim3(256), 0, stream,
                           robot_h, agg, W_pr + l * 512 * 256, b_pr + l * 256,
                           g_r + l * 256, be_r + l * 256,
                           W2a, o2a, (const float*)nullptr, (const float*)nullptr, (float*)nullptr);
    }

    hipLaunchKernelGGL(k_scores, dim3(128), dim3(256), 0, stream, rS, tST, Ws2, bs2, scores);
    hipLaunchKernelGGL(k_sinkhorn, dim3(8), dim3(256), 0, stream, scores, probs);
}

// Round 3
// 411.509 us; speedup vs baseline: 2.2159x; 1.0872x over previous
//
#include <hip/hip_runtime.h>

// NavAssignNet on MI355X — round 3.
//   - k_update rewritten as MFMA with 3-term bf16 hi/lo split (fp32-class accuracy)
//   - W^T hi/lo planes precomputed once (k_split)
//   - k_prep re-gridded to 512 WGs
//   - everything else carried from round 2

typedef short bf16x8 __attribute__((ext_vector_type(8)));
typedef float f32x4 __attribute__((ext_vector_type(4)));

#define DEV static __device__ __forceinline__

DEV unsigned short f2bf(float x) {
    unsigned u = __float_as_uint(x);
    return (unsigned short)((u + 0x7fffu + ((u >> 16) & 1u)) >> 16);
}
DEV void split2(float v, unsigned short& hi, unsigned short& lo) {
    unsigned short h = f2bf(v);
    float fh = __uint_as_float(((unsigned)h) << 16);
    hi = h;
    lo = f2bf(v - fh);
}

// ---- 1. prep: edge_raw -> bf16 AND traw = mean over i, 512 WGs ----
__global__ __launch_bounds__(256) void k_prep(const float* __restrict__ edge,
                                              unsigned short* __restrict__ edge_bf,
                                              float* __restrict__ traw) {
    int wg = blockIdx.x;                 // 512 = b*64 + j
    int b = wg >> 6, j = wg & 63;
    int t = threadIdx.x;
    int d = t & 127, ih = t >> 7;        // ih: i-half
    float s = 0.f;
    long base = ((long)(b * 64 + ih * 32) * 64 + j) * 128 + d;
#pragma unroll 8
    for (int ii = 0; ii < 32; ++ii) {
        long idx = base + (long)ii * 8192;
        float v = edge[idx];
        s += v;
        edge_bf[idx] = f2bf(v);
    }
    __shared__ float part[128];
    if (ih == 1) part[d] = s;
    __syncthreads();
    if (ih == 0) traw[(b * 64 + j) * 128 + d] = (s + part[d]) * (1.f / 64.f);
}

// ---- 2. WcT[p][h][d] = (Wp @ Wb_p)^T (bf16), bc[p][h] = bp@Wb_p + b_msg ----
__global__ __launch_bounds__(256) void k_wc(const float* __restrict__ Wp,
                                            const float* __restrict__ bp,
                                            const float* __restrict__ W_r2t,
                                            const float* __restrict__ b_r2t,
                                            const float* __restrict__ W_t2r,
                                            const float* __restrict__ b_t2r,
                                            unsigned short* __restrict__ WcT,
                                            float* __restrict__ bc) {
    int blk = blockIdx.x;
    int h = threadIdx.x;
    if (blk < 768) {
        int p = blk >> 7, d = blk & 127, l = p >> 1;
        const float* Wb = ((p & 1) ? W_t2r : W_r2t) + l * 512 * 256 + 256 * 256;
        float acc = 0.f;
        for (int k = 0; k < 256; ++k) acc += Wp[d * 256 + k] * Wb[k * 256 + h];
        WcT[p * 32768 + h * 128 + d] = f2bf(acc);
    } else {
        int p = blk - 768, l = p >> 1;
        const float* Wb = ((p & 1) ? W_t2r : W_r2t) + l * 512 * 256 + 256 * 256;
        const float* bm = ((p & 1) ? b_t2r : b_r2t) + l * 256;
        float acc = bm[h];
        for (int k = 0; k < 256; ++k) acc += bp[k] * Wb[k * 256 + h];
        bc[p * 256 + h] = acc;
    }
}

// ---- 3. split: W^T hi/lo bf16 planes for update GEMMs ----
// big mats (512x256): mat 2l = W_pt[l], 2l+1 = W_pr[l] -> WTbig[mat][{hi,lo}][256][512]
// small mats (256x256): 0,2,4 = W_t2r[l][:256]; 1,3 = W_r2t[l+1][:256]; 5 = Ws1[:256]; 6 = Ws1[256:]
__global__ __launch_bounds__(256) void k_split(const float* __restrict__ W_pt,
                                               const float* __restrict__ W_pr,
                                               const float* __restrict__ W_t2r,
                                               const float* __restrict__ W_r2t,
                                               const float* __restrict__ Ws1,
                                               unsigned short* __restrict__ WTbig,
                                               unsigned short* __restrict__ WT2) {
    int blk = blockIdx.x, t = threadIdx.x;
    if (blk < 1536) {
        int mat = blk >> 8, h = blk & 255, l = mat >> 1;
        const float* W = ((mat & 1) ? W_pr : W_pt) + l * 512 * 256;
        unsigned short* dh = WTbig + mat * 262144 + h * 512;
        unsigned short* dl = dh + 131072;
        for (int k = t; k < 512; k += 256) {
            unsigned short hi, lo;
            split2(W[k * 256 + h], hi, lo);
            dh[k] = hi; dl[k] = lo;
        }
    } else {
        int m2 = blk - 1536, mat = m2 >> 8, h = m2 & 255;
        const float* W;
        if (mat == 6) W = Ws1 + 256 * 256;
        else if (mat == 5) W = Ws1;
        else if (mat & 1) W = W_r2t + ((mat >> 1) + 1) * 512 * 256;
        else W = W_t2r + (mat >> 1) * 512 * 256;
        unsigned short* dh = WT2 + mat * 131072 + h * 256;
        unsigned short* dl = dh + 65536;
        unsigned short hi, lo;
        split2(W[t * 256 + h], hi, lo);
        dh[t] = hi; dl[t] = lo;
    }
}

// ---- 4. proj: robot_h/target_h = X @ Wp + bp ; robot WGs also emit rWa0 ----
__global__ __launch_bounds__(256) void k_proj(const float* __restrict__ robot_raw,
                                              const float* __restrict__ traw,
                                              const float* __restrict__ Wp,
                                              const float* __restrict__ bp,
                                              const float* __restrict__ Wa0,
                                              float* __restrict__ robot_h,
                                              float* __restrict__ target_h,
                                              float* __restrict__ rWa) {
    int h = threadIdx.x;
    int r0 = blockIdx.x * 2;
    int robot = (r0 < 512);
    const float* in;
    float* out;
    if (robot) { in = robot_raw + r0 * 128; out = robot_h + r0 * 256; }
    else       { in = traw + (r0 - 512) * 128; out = target_h + (r0 - 512) * 256; }
    float a0 = 0, a1 = 0;
    for (int k = 0; k < 128; ++k) {
        float w = Wp[k * 256 + h];
        a0 += in[k] * w; a1 += in[128 + k] * w;
    }
    float b = bp[h];
    a0 += b; a1 += b;
    out[h] = a0; out[256 + h] = a1;

    __shared__ float yl[2][257];
    if (robot) { yl[0][h] = a0; yl[1][h] = a1; }
    __syncthreads();
    if (robot) {
        float c0 = 0, c1 = 0;
        for (int k = 0; k < 256; ++k) {
            float w = Wa0[k * 256 + h];
            c0 += yl[0][k] * w; c1 += yl[1][k] * w;
        }
        rWa[r0 * 256 + h] = c0; rWa[(r0 + 1) * 256 + h] = c1;
    }
}

// ---- 5. update via MFMA split-bf16: state = LN(state + [state;agg]@W + b); fused y@W2a (+ y@W2b) ----
// 32 WGs x 16 rows, 4 waves each covering 64 cols.
__global__ __launch_bounds__(256) void k_update_mfma(
        float* __restrict__ state, const float* __restrict__ agg,
        const unsigned short* __restrict__ WTm,   // [hi 256x512][lo 256x512]
        const float* __restrict__ bvec, const float* __restrict__ g, const float* __restrict__ be,
        const unsigned short* __restrict__ WT2a,  // [hi 256x256][lo 256x256]
        float* __restrict__ out2a,
        const unsigned short* __restrict__ WT2b, const float* __restrict__ b2b,
        float* __restrict__ out2b) {
    int r0 = blockIdx.x * 16;
    int t = threadIdx.x;
    int w = t >> 6, lane = t & 63;
    int c16 = lane & 15, kg = lane >> 4;
    int colbase = 64 * w + c16;

    __shared__ unsigned short Ahi[16 * 512];
    __shared__ unsigned short Alo[16 * 512];
    __shared__ unsigned short Yhi[16 * 256];
    __shared__ unsigned short Ylo[16 * 256];
    __shared__ float red[4][16][2];

    // stage A = [state | agg] rows r0..r0+15 as swizzled hi/lo bf16
    {
        int row = t & 15, kq = t >> 4;   // kq 0..15 -> 32 K-elems each
        const float* src = (kq < 8) ? (state + (r0 + row) * 256 + kq * 32)
                                    : (agg + (r0 + row) * 256 + (kq - 8) * 32);
#pragma unroll
        for (int blk = 0; blk < 4; ++blk) {
            float4 a = *(const float4*)(src + blk * 8);
            float4 b2 = *(const float4*)(src + blk * 8 + 4);
            unsigned short h[8], lo[8];
            split2(a.x, h[0], lo[0]); split2(a.y, h[1], lo[1]);
            split2(a.z, h[2], lo[2]); split2(a.w, h[3], lo[3]);
            split2(b2.x, h[4], lo[4]); split2(b2.y, h[5], lo[5]);
            split2(b2.z, h[6], lo[6]); split2(b2.w, h[7], lo[7]);
            int byte = row * 1024 + (kq * 32 + blk * 8) * 2;
            byte ^= (row & 7) << 4;
            ushort4* ph = (ushort4*)((char*)Ahi + byte);
            ph[0] = make_ushort4(h[0], h[1], h[2], h[3]);
            ph[1] = make_ushort4(h[4], h[5], h[6], h[7]);
            ushort4* pl = (ushort4*)((char*)Alo + byte);
            pl[0] = make_ushort4(lo[0], lo[1], lo[2], lo[3]);
            pl[1] = make_ushort4(lo[4], lo[5], lo[6], lo[7]);
        }
    }
    __syncthreads();

    // main GEMM: K=512, 3-term split
    f32x4 acc[4];
#pragma unroll
    for (int ni = 0; ni < 4; ++ni) acc[ni] = f32x4{0.f, 0.f, 0.f, 0.f};
    const unsigned short* Bh0 = WTm + colbase * 512 + kg * 8;
#pragma unroll 2
    for (int ks = 0; ks < 16; ++ks) {
        int ab = c16 * 1024 + ks * 64 + kg * 16;
        ab ^= (c16 & 7) << 4;
        bf16x8 ah = *(const bf16x8*)((const char*)Ahi + ab);
        bf16x8 al = *(const bf16x8*)((const char*)Alo + ab);
#pragma unroll
        for (int ni = 0; ni < 4; ++ni) {
            const unsigned short* p = Bh0 + ni * 16 * 512 + ks * 32;
            bf16x8 bh = *(const bf16x8*)p;
            bf16x8 bl = *(const bf16x8*)(p + 131072);
            acc[ni] = __builtin_amdgcn_mfma_f32_16x16x32_bf16(ah, bh, acc[ni], 0, 0, 0);
            acc[ni] = __builtin_amdgcn_mfma_f32_16x16x32_bf16(al, bh, acc[ni], 0, 0, 0);
            acc[ni] = __builtin_amdgcn_mfma_f32_16x16x32_bf16(ah, bl, acc[ni], 0, 0, 0);
        }
    }

    // residual + bias: x[ni][r], rows rowC = kg*4+r, col = colbase+16*ni
    float x[4][4];
#pragma unroll
    for (int ni = 0; ni < 4; ++ni) {
        int col = colbase + 16 * ni;
        float bv = bvec[col];
#pragma unroll
        for (int r = 0; r < 4; ++r) {
            int row = kg * 4 + r;
            x[ni][r] = acc[ni][r] + state[(r0 + row) * 256 + col] + bv;
        }
    }

    // LN stats
    float s[4], q[4];
#pragma unroll
    for (int r = 0; r < 4; ++r) {
        s[r] = x[0][r] + x[1][r] + x[2][r] + x[3][r];
        q[r] = x[0][r] * x[0][r] + x[1][r] * x[1][r] + x[2][r] * x[2][r] + x[3][r] * x[3][r];
#pragma unroll
        for (int m = 1; m < 16; m <<= 1) {
            s[r] += __shfl_xor(s[r], m);
            q[r] += __shfl_xor(q[r], m);
        }
    }
    if (c16 == 0) {
#pragma unroll
        for (int r = 0; r < 4; ++r) {
            red[w][kg * 4 + r][0] = s[r];
            red[w][kg * 4 + r][1] = q[r];
        }
    }
    __syncthreads();
    float mr[4], rsr[4];
#pragma unroll
    for (int r = 0; r < 4; ++r) {
        int row = kg * 4 + r;
        float S = red[0][row][0] + red[1][row][0] + red[2][row][0] + red[3][row][0];
        float Q = red[0][row][1] + red[1][row][1] + red[2][row][1] + red[3][row][1];
        float m = S * (1.f / 256.f);
        float v = Q * (1.f / 256.f) - m * m;
        mr[r] = m;
        rsr[r] = rsqrtf(v + 1e-5f);
    }

    // y = LN(x): store to state + stage bf16 hi/lo into LDS (swizzled)
#pragma unroll
    for (int ni = 0; ni < 4; ++ni) {
        int col = colbase + 16 * ni;
        float gg = g[col], bb = be[col];
#pragma unroll
        for (int r = 0; r < 4; ++r) {
            int row = kg * 4 + r;
            float y = (x[ni][r] - mr[r]) * rsr[r] * gg + bb;
            state[(r0 + row) * 256 + col] = y;
            unsigned short yh, yl2;
            split2(y, yh, yl2);
            int byte = (row * 512 + col * 2) ^ ((row & 7) << 4);
            *(unsigned short*)((char*)Yhi + byte) = yh;
            *(unsigned short*)((char*)Ylo + byte) = yl2;
        }
    }
    __syncthreads();

    // fused GEMM(s): y @ W2a (-> out2a), optional y @ W2b + b2b (-> out2b transposed)
    f32x4 acc2[4], acc3[4];
#pragma unroll
    for (int ni = 0; ni < 4; ++ni) { acc2[ni] = f32x4{0.f, 0.f, 0.f, 0.f}; acc3[ni] = f32x4{0.f, 0.f, 0.f, 0.f}; }
    const unsigned short* B2h0 = WT2a + colbase * 256 + kg * 8;
    const unsigned short* B3h0 = WT2b ? (WT2b + colbase * 256 + kg * 8) : B2h0;
    int haveB = (WT2b != nullptr);
#pragma unroll 2
    for (int ks = 0; ks < 8; ++ks) {
        int ab = c16 * 512 + ks * 64 + kg * 16;
        ab ^= (c16 & 7) << 4;
        bf16x8 ah = *(const bf16x8*)((const char*)Yhi + ab);
        bf16x8 al = *(const bf16x8*)((const char*)Ylo + ab);
#pragma unroll
        for (int ni = 0; ni < 4; ++ni) {
            const unsigned short* p = B2h0 + ni * 16 * 256 + ks * 32;
            bf16x8 bh = *(const bf16x8*)p;
            bf16x8 bl = *(const bf16x8*)(p + 65536);
            acc2[ni] = __builtin_amdgcn_mfma_f32_16x16x32_bf16(ah, bh, acc2[ni], 0, 0, 0);
            acc2[ni] = __builtin_amdgcn_mfma_f32_16x16x32_bf16(al, bh, acc2[ni], 0, 0, 0);
            acc2[ni] = __builtin_amdgcn_mfma_f32_16x16x32_bf16(ah, bl, acc2[ni], 0, 0, 0);
            if (haveB) {
                const unsigned short* p3 = B3h0 + ni * 16 * 256 + ks * 32;
                bf16x8 bh3 = *(const bf16x8*)p3;
                bf16x8 bl3 = *(const bf16x8*)(p3 + 65536);
                acc3[ni] = __builtin_amdgcn_mfma_f32_16x16x32_bf16(ah, bh3, acc3[ni], 0, 0, 0);
                acc3[ni] = __builtin_amdgcn_mfma_f32_16x16x32_bf16(al, bh3, acc3[ni], 0, 0, 0);
                acc3[ni] = __builtin_amdgcn_mfma_f32_16x16x32_bf16(ah, bl3, acc3[ni], 0, 0, 0);
            }
        }
    }
#pragma unroll
    for (int ni = 0; ni < 4; ++ni) {
        int col = colbase + 16 * ni;
#pragma unroll
        for (int r = 0; r < 4; ++r) {
            int row = kg * 4 + r;
            out2a[(r0 + row) * 256 + col] = acc2[ni][r];
        }
    }
    if (haveB) {
#pragma unroll
        for (int ni = 0; ni < 4; ++ni) {
            int col = colbase + 16 * ni;
            float bb2 = b2b[col];
#pragma unroll
            for (int r = 0; r < 4; ++r) {
                int grow = r0 + kg * 4 + r;
                int b0 = grow >> 6, j = grow & 63;
                out2b[(b0 * 256 + col) * 64 + j] = acc3[ni][r] + bb2;
            }
        }
    }
}

// ---- 6. bigpass: agg[b,jj,h] = mean_rows relu(edge_raw@Wc + rowbias + bc), MFMA bf16 ----
__global__ __launch_bounds__(256) void k_bigpass(const unsigned short* __restrict__ edge_bf,
                                                 const unsigned short* __restrict__ WcT,
                                                 const float* __restrict__ bc,
                                                 const float* __restrict__ rowbias,
                                                 float* __restrict__ agg,
                                                 int mode) {
    int wg = blockIdx.x;                 // 512 = b*64 + jj
    int b = wg >> 6, jj = wg & 63;
    int w = threadIdx.x >> 6, lane = threadIdx.x & 63;
    int row16 = lane & 15, kgrp = lane >> 4;

    int rstride = (mode == 0) ? 8192 : 128;
    const unsigned short* A = edge_bf + b * 524288 + ((mode == 0) ? jj * 128 : jj * 8192);
    const unsigned short* Ap = A + row16 * rstride + 8 * kgrp;
    const unsigned short* Bp = WcT + (64 * w + row16) * 128 + 8 * kgrp;

    f32x4 acc[4][4];
#pragma unroll
    for (int mi = 0; mi < 4; ++mi)
#pragma unroll
        for (int ni = 0; ni < 4; ++ni) acc[mi][ni] = f32x4{0.f, 0.f, 0.f, 0.f};

#pragma unroll
    for (int kk = 0; kk < 4; ++kk) {
        bf16x8 av[4], bv[4];
#pragma unroll
        for (int mi = 0; mi < 4; ++mi)
            av[mi] = *(const bf16x8*)(Ap + mi * 16 * rstride + kk * 32);
#pragma unroll
        for (int ni = 0; ni < 4; ++ni)
            bv[ni] = *(const bf16x8*)(Bp + ni * 16 * 128 + kk * 32);
#pragma unroll
        for (int mi = 0; mi < 4; ++mi)
#pragma unroll
            for (int ni = 0; ni < 4; ++ni)
                acc[mi][ni] = __builtin_amdgcn_mfma_f32_16x16x32_bf16(av[mi], bv[ni], acc[mi][ni], 0, 0, 0);
    }

    const float* rb = rowbias + (b * 64) * 256;
    float colsum[4] = {0.f, 0.f, 0.f, 0.f};
#pragma unroll
    for (int ni = 0; ni < 4; ++ni) {
        int col = 64 * w + 16 * ni + row16;
        float bch = bc[col];
#pragma unroll
        for (int mi = 0; mi < 4; ++mi) {
            int rbase = 16 * mi + 4 * kgrp;
#pragma unroll
            for (int r = 0; r < 4; ++r) {
                float v = acc[mi][ni][r] + rb[(rbase + r) * 256 + col] + bch;
                colsum[ni] += fmaxf(v, 0.f);
            }
        }
    }
#pragma unroll
    for (int ni = 0; ni < 4; ++ni) {
        colsum[ni] += __shfl_xor(colsum[ni], 16);
        colsum[ni] += __shfl_xor(colsum[ni], 32);
    }
    if (kgrp == 0) {
        float* o = agg + (b * 64 + jj) * 256 + 64 * w + row16;
#pragma unroll
        for (int ni = 0; ni < 4; ++ni) o[16 * ni] = colsum[ni] * (1.f / 64.f);
    }
}

// ---- 7. scores ----
__global__ __launch_bounds__(256) void k_scores(const float* __restrict__ rS,
                                                const float* __restrict__ tST,
                                                const float* __restrict__ Ws2,
                                                const float* __restrict__ bs2,
                                                float* __restrict__ scores) {
    int t = blockIdx.x * 256 + threadIdx.x;          // 32768
    int j = t & 63, i = (t >> 6) & 63, b = t >> 12;
    const float* rs = rS + (b * 64 + i) * 256;
    const float* ts = tST + b * 256 * 64 + j;
    float acc = bs2[0];
    for (int h = 0; h < 256; ++h)
        acc += fmaxf(rs[h] + ts[h * 64], 0.f) * Ws2[h];
    scores[t] = acc;
}

// ---- 8. sinkhorn: register-resident ----
__global__ __launch_bounds__(256) void k_sinkhorn(const float* __restrict__ scores,
                                                  float* __restrict__ probs) {
    int b = blockIdx.x;
    int t = threadIdx.x;
    int j = t & 63, rg = t >> 6;
    float v[16];
    const float* src = scores + b * 4096 + rg * 1024 + j;
#pragma unroll
    for (int k = 0; k < 16; ++k) v[k] = src[k * 64];

    __shared__ float lm_s[4][64];
    __shared__ float ps_s[4][64];

    for (int it = 0; it < 10; ++it) {
#pragma unroll
        for (int k = 0; k < 16; ++k) {
            float m = v[k];
#pragma unroll
            for (int s = 1; s < 64; s <<= 1) m = fmaxf(m, __shfl_xor(m, s));
            float e = __expf(v[k] - m), ss = e;
#pragma unroll
            for (int s = 1; s < 64; s <<= 1) ss += __shfl_xor(ss, s);
            v[k] -= m + __logf(ss);
        }
        float lm = v[0];
#pragma unroll
        for (int k = 1; k < 16; ++k) lm = fmaxf(lm, v[k]);
        float ps = 0.f;
#pragma unroll
        for (int k = 0; k < 16; ++k) ps += __expf(v[k] - lm);
        lm_s[rg][j] = lm; ps_s[rg][j] = ps;
        __syncthreads();
        float m0 = lm_s[0][j], m1 = lm_s[1][j], m2 = lm_s[2][j], m3 = lm_s[3][j];
        float M = fmaxf(fmaxf(m0, m1), fmaxf(m2, m3));
        float S = ps_s[0][j] * __expf(m0 - M) + ps_s[1][j] * __expf(m1 - M)
                + ps_s[2][j] * __expf(m2 - M) + ps_s[3][j] * __expf(m3 - M);
        float lse = M + __logf(S);
#pragma unroll
        for (int k = 0; k < 16; ++k) v[k] -= lse;
        __syncthreads();
    }
    float* dst = probs + b * 4096 + rg * 1024 + j;
#pragma unroll
    for (int k = 0; k < 16; ++k) dst[k * 64] = __expf(v[k]);
}

extern "C" void kernel_launch(void* const* d_in, const int* in_sizes, int n_in,
                              void* d_out, int out_size, void* d_ws, size_t ws_size,
                              hipStream_t stream) {
    const float* robot_raw = (const float*)d_in[0];
    const float* edge_raw  = (const float*)d_in[1];
    const float* Wp    = (const float*)d_in[2];
    const float* bp    = (const float*)d_in[3];
    const float* W_r2t = (const float*)d_in[4];
    const float* b_r2t = (const float*)d_in[5];
    const float* W_pt  = (const float*)d_in[6];
    const float* b_pt  = (const float*)d_in[7];
    const float* g_t   = (const float*)d_in[8];
    const float* be_t  = (const float*)d_in[9];
    const float* W_t2r = (const float*)d_in[10];
    const float* b_t2r = (const float*)d_in[11];
    const float* W_pr  = (const float*)d_in[12];
    const float* b_pr  = (const float*)d_in[13];
    const float* g_r   = (const float*)d_in[14];
    const float* be_r  = (const float*)d_in[15];
    const float* Ws1   = (const float*)d_in[16];
    const float* bs1   = (const float*)d_in[17];
    const float* Ws2   = (const float*)d_in[18];
    const float* bs2   = (const float*)d_in[19];

    char* ws = (char*)d_ws;
    unsigned short* edge_bf = (unsigned short*)(ws);            // 8,388,608
    float* traw     = (float*)(ws + 8388608);                   //   262,144
    float* robot_h  = (float*)(ws + 8650752);                   //   524,288
    float* target_h = (float*)(ws + 9175040);                   //   524,288
    unsigned short* WcT = (unsigned short*)(ws + 9699328);      //   393,216
    float* bc       = (float*)(ws + 10092544);                  //     6,144
    float* rWa      = (float*)(ws + 10098688);                  //   524,288
    float* tWa      = (float*)(ws + 10622976);                  //   524,288
    float* agg      = (float*)(ws + 11147264);                  //   524,288
    float* rS       = (float*)(ws + 11671552);                  //   524,288
    float* tST      = (float*)(ws + 12195840);                  //   524,288
    unsigned short* WTbig = (unsigned short*)(ws + 12720128);   // 3,145,728
    unsigned short* WT2   = (unsigned short*)(ws + 15865856);   // 1,835,008

    float* out    = (float*)d_out;
    float* probs  = out;            // output 0
    float* scores = out + 32768;    // output 1

    hipLaunchKernelGGL(k_prep, dim3(512), dim3(256), 0, stream, edge_raw, edge_bf, traw);
    hipLaunchKernelGGL(k_wc, dim3(774), dim3(256), 0, stream, Wp, bp, W_r2t, b_r2t, W_t2r, b_t2r, WcT, bc);
    hipLaunchKernelGGL(k_split, dim3(3328), dim3(256), 0, stream, W_pt, W_pr, W_t2r, W_r2t, Ws1, WTbig, WT2);
    hipLaunchKernelGGL(k_proj, dim3(512), dim3(256), 0, stream,
                       robot_raw, traw, Wp, bp, W_r2t, robot_h, target_h, rWa);

    for (int l = 0; l < 3; ++l) {
        hipLaunchKernelGGL(k_bigpass, dim3(512), dim3(256), 0, stream,
                           edge_bf, WcT + (2 * l) * 32768, bc + (2 * l) * 256, rWa, agg, 0);
        const unsigned short* W2b = (l == 2) ? (WT2 + 6 * 131072) : nullptr;
        const float* b2b = (l == 2) ? bs1 : nullptr;
        float* o2b = (l == 2) ? tST : nullptr;
        hipLaunchKernelGGL(k_update_mfma, dim3(32), dim3(256), 0, stream,
                           target_h, agg, WTbig + (2 * l) * 262144,
                           b_pt + l * 256, g_t + l * 256, be_t + l * 256,
                           WT2 + (2 * l) * 131072, tWa, W2b, b2b, o2b);
        hipLaunchKernelGGL(k_bigpass, dim3(512), dim3(256), 0, stream,
                           edge_bf, WcT + (2 * l + 1) * 32768, bc + (2 * l + 1) * 256, tWa, agg, 1);
        const unsigned short* W2a = (l < 2) ? (WT2 + (2 * l + 1) * 131072) : (WT2 + 5 * 131072);
        float* o2a = (l < 2) ? rWa : rS;
        hipLaunchKernelGGL(k_update_mfma, dim3(32), dim3(256), 0, stream,
                           robot_h, agg, WTbig + (2 * l + 1) * 262144,
                           b_pr + l * 256, g_r + l * 256, be_r + l * 256,
                           W2a, o2a, (const unsigned short*)nullptr, (const float*)nullptr, (float*)nullptr);
    }

    hipLaunchKernelGGL(k_scores, dim3(128), dim3(256), 0, stream, rS, tST, Ws2, bs2, scores);
    hipLaunchKernelGGL(k_sinkhorn, dim3(8), dim3(256), 0, stream, scores, probs);
}